// Round 1
// 477.320 us; speedup vs baseline: 1.3328x; 1.3328x over previous
//
#include <hip/hip_runtime.h>
#include <math.h>

#define B_TOT 1024
#define T_LEN 4096
#define K_TAGS 16
#define START_TAG 14
#define STOP_TAG 15

#define LOG2E 1.4426950408889634f
#define LN2 0.6931471805599453f

#define CH 64                 // timesteps per staged chunk
#define NCH (T_LEN / CH)      // 64 chunks total
#define NCHH (NCH / 2)        // 32 chunks per half
#define ROWW 1032             // padded words per batch-row per buffer (64*16 + 8)
#define FBW (4 * ROWW)        // words per buffer (4 batch rows)

// workspace layout (float indices)
#define WS_VF 0               // [1024*16] forward half-vectors
#define WS_VB 16384           // [1024*16] backward half-vectors
#define WS_GF 32768           // [1024] gold partial, forward (+boundary)
#define WS_GB 33792           // [1024] gold partial, backward (+STOP term)
#define WS_CF 34816           // [1024] int: forward log2 scale
#define WS_CB 35840           // [1024] int: backward log2 scale

typedef __attribute__((address_space(1))) const void GVoid;
typedef __attribute__((address_space(3))) void LVoid;

#define ROTV(v, I) __int_as_float(__builtin_amdgcn_mov_dpp(__float_as_int(v), 0x120 + (I), 0xF, 0xF, false))

// Bidirectional bilinear split: result = log( r^T A2 A1 e_START ), r = exp(trans[STOP,:]).
// Blocks 0..255:   forward  v = A1 e_START   over t in [0, 2048)       (matvec then *ef)
// Blocks 256..511: backward w = A2^T r       over t in [4095, 2048]    (*ef then transposed matvec)
// Each half is the same serial cost per step; serial depth halves 4096 -> 2048,
// wave count doubles 256 -> 512 (2 waves/CU). Combine kernel does the dot product.
__global__ __launch_bounds__(64, 1) void crf_half_kernel(
        const float* __restrict__ feats,
        const int* __restrict__ tags,
        const float* __restrict__ trans,
        float* __restrict__ ws) {
    __shared__ float FBraw[128 + 2 * FBW + 160];  // +128 leading slack for backward ring underrun
    __shared__ int TG[2][4 * CH];                 // tag buffers
    __shared__ float TlS[K_TAGS * K_TAGS];        // raw transitions
    __shared__ int edgeRow[4];                    // gold chain carry (prev tag fwd / next tag bwd)

    float* const FB = FBraw + 128;

    const int lane = threadIdx.x;
    const int r = lane >> 4;
    const int j = lane & 15;
    const int half = blockIdx.x >> 8;             // 0 = forward, 1 = backward
    const int bbase = (blockIdx.x & 255) * 4;

    for (int i = lane; i < K_TAGS * K_TAGS; i += 64) TlS[i] = trans[i];
    if (lane < 4) edgeRow[lane] = half ? STOP_TAG : START_TAG;
    __syncthreads();

    // --- DPP direction probe: after row_ror:1, lane j holds value from lane (j+d)&15 ---
    const int pv = __builtin_amdgcn_mov_dpp(j, 0x121, 0xF, 0xF, false);
    const int d = (pv - j) & 15;  // 1 or 15

    // et[i] pairs with rotation amount i: rotated vector delivers x[(j + d*i)&15].
    // forward: coeff = M[j, src] ; backward (transposed matvec): coeff = M[src, j]
    float et[K_TAGS];
#pragma unroll
    for (int i = 0; i < K_TAGS; ++i) {
        const int src = (j + d * i) & 15;
        et[i] = exp2f(TlS[half ? (src * K_TAGS + j) : (j * K_TAGS + src)] * LOG2E);
    }

    const int rowbase = (lane & ~15) << 2;  // byte index of lane r*16 (bpermute)

    // --- async stage of one chunk (16 feat loads + 4 tag loads = 20 vm ops) ---
    auto stage = [&](int c, int pb) {
        const int t0 = c * CH;
#pragma unroll
        for (int i = 0; i < 16; ++i) {
            const int row = i >> 2, seg = i & 3;
            const float* g = feats + ((size_t)(bbase + row) * T_LEN + t0) * K_TAGS
                             + seg * 256 + lane * 4;
            const float* l = &FB[pb * FBW + row * ROWW + seg * 256];
            __builtin_amdgcn_global_load_lds((GVoid*)g, (LVoid*)l, 16, 0, 0);
        }
#pragma unroll
        for (int row = 0; row < 4; ++row) {
            const int* g = tags + (size_t)(bbase + row) * T_LEN + t0 + lane;
            const int* l = &TG[pb][row * CH];
            __builtin_amdgcn_global_load_lds((GVoid*)g, (LVoid*)l, 4, 0, 0);
        }
    };

    float s = half ? exp2f(TlS[STOP_TAG * K_TAGS + j] * LOG2E)   // r[j]; -1e4 entries underflow to 0
                   : ((j == START_TAG) ? 1.0f : 0.0f);
    int Cacc = 0;        // accumulated log2 scale (exact int)
    float bp = 1.0f;     // row-reference (lane 0 of row), captured every 8th step
    int kprev = 0;       // exponent correction extracted from bp (8 steps stale)
    float gold = 0.0f;   // per-lane gold partial (sidecar)

    if (!half) {
        // ===================== FORWARD HALF: chunks 0..31 =====================
        stage(0, 0);
        for (int c = 0; c < NCHH; ++c) {
            const int pb = c & 1;
            if (c + 1 < NCHH) {
                stage(c + 1, pb ^ 1);
                __builtin_amdgcn_s_waitcnt(0x4F74);  // vmcnt<=20
            } else {
                __builtin_amdgcn_s_waitcnt(0x0F70);  // vmcnt(0)
            }
            __builtin_amdgcn_sched_barrier(0);

            const float* fp = &FB[pb * FBW + r * ROWW + j];
            float fr[8];
#pragma unroll
            for (int u = 0; u < 8; ++u) fr[u] = fp[u * 16];

            for (int tb = 0; tb < CH; tb += 8) {
                const float* fq = fp + (tb + 8) * 16;  // refill base (overrun -> slack)
#pragma unroll
                for (int u = 0; u < 8; ++u) {
                    const float f = fr[u];
                    fr[u] = fq[u * 16];

                    float ef;
                    if (u == 7) {
                        kprev = (((__float_as_int(bp) >> 23) & 0xFF) - 127);
                        Cacc += 32 + kprev;
                        ef = exp2f(fmaf(f, LOG2E, -(4.0f + (float)kprev)));
                    } else {
                        ef = exp2f(fmaf(f, LOG2E, -4.0f));
                    }

                    float a0 = s * et[0];
                    float a1 = ROTV(s, 1) * et[1];
                    float a2 = ROTV(s, 2) * et[2];
                    float a3 = ROTV(s, 3) * et[3];
                    a0 = fmaf(ROTV(s, 4), et[4], a0);
                    a1 = fmaf(ROTV(s, 5), et[5], a1);
                    a2 = fmaf(ROTV(s, 6), et[6], a2);
                    a3 = fmaf(ROTV(s, 7), et[7], a3);
                    a0 = fmaf(ROTV(s, 8), et[8], a0);
                    a1 = fmaf(ROTV(s, 9), et[9], a1);
                    a2 = fmaf(ROTV(s, 10), et[10], a2);
                    a3 = fmaf(ROTV(s, 11), et[11], a3);
                    a0 = fmaf(ROTV(s, 12), et[12], a0);
                    a1 = fmaf(ROTV(s, 13), et[13], a1);
                    a2 = fmaf(ROTV(s, 14), et[14], a2);
                    a3 = fmaf(ROTV(s, 15), et[15], a3);
                    s = ((a0 + a1) + (a2 + a3)) * ef;

                    if (u == 7)
                        bp = __int_as_float(__builtin_amdgcn_ds_bpermute(
                                rowbase, __float_as_int(s)));
                }
            }

            // gold sidecar: transitions ENTERING t, prev carried; lane j owns [4j, 4j+4)
            {
                const int* tg = &TG[pb][r * CH];
                const int t4 = j * 4;
                const int pidx = (j == 0) ? 0 : (t4 - 1);
                const int pval = tg[pidx];
                int prev = (j == 0) ? edgeRow[r] : pval;
                const float* fbase = &FB[pb * FBW + r * ROWW];
#pragma unroll
                for (int q = 0; q < 4; ++q) {
                    const int tc = tg[t4 + q];
                    gold += TlS[tc * K_TAGS + prev];
                    gold += fbase[(t4 + q) * 16 + tc];
                    prev = tc;
                }
                if (j == 15) edgeRow[r] = prev;  // ends as tags[2047]
            }
        }
    } else {
        // ===================== BACKWARD HALF: chunks 63..32 =====================
        stage(NCH - 1, 0);
        for (int ii = 0; ii < NCHH; ++ii) {
            const int pb = ii & 1;
            if (ii + 1 < NCHH) {
                stage(NCH - 2 - ii, pb ^ 1);
                __builtin_amdgcn_s_waitcnt(0x4F74);  // vmcnt<=20
            } else {
                __builtin_amdgcn_s_waitcnt(0x0F70);  // vmcnt(0)
            }
            __builtin_amdgcn_sched_barrier(0);

            const float* fp = &FB[pb * FBW + r * ROWW + j];
            float fr[8];
#pragma unroll
            for (int u = 0; u < 8; ++u) fr[u] = fp[(CH - 1 - u) * 16];

            for (int tb = 0; tb < CH; tb += 8) {
                const float* fq = fp + (CH - 9 - tb) * 16;  // fr[u] <- t_loc 55-tb-u (underrun -> slack)
#pragma unroll
                for (int u = 0; u < 8; ++u) {
                    const float f = fr[u];
                    fr[u] = fq[-(u * 16)];

                    float ef;
                    if (u == 7) {
                        kprev = (((__float_as_int(bp) >> 23) & 0xFF) - 127);
                        Cacc += 32 + kprev;
                        ef = exp2f(fmaf(f, LOG2E, -(4.0f + (float)kprev)));
                    } else {
                        ef = exp2f(fmaf(f, LOG2E, -4.0f));
                    }

                    const float us = s * ef;  // scale-then-matvec (transposed)
                    float a0 = us * et[0];
                    float a1 = ROTV(us, 1) * et[1];
                    float a2 = ROTV(us, 2) * et[2];
                    float a3 = ROTV(us, 3) * et[3];
                    a0 = fmaf(ROTV(us, 4), et[4], a0);
                    a1 = fmaf(ROTV(us, 5), et[5], a1);
                    a2 = fmaf(ROTV(us, 6), et[6], a2);
                    a3 = fmaf(ROTV(us, 7), et[7], a3);
                    a0 = fmaf(ROTV(us, 8), et[8], a0);
                    a1 = fmaf(ROTV(us, 9), et[9], a1);
                    a2 = fmaf(ROTV(us, 10), et[10], a2);
                    a3 = fmaf(ROTV(us, 11), et[11], a3);
                    a0 = fmaf(ROTV(us, 12), et[12], a0);
                    a1 = fmaf(ROTV(us, 13), et[13], a1);
                    a2 = fmaf(ROTV(us, 14), et[14], a2);
                    a3 = fmaf(ROTV(us, 15), et[15], a3);
                    s = (a0 + a1) + (a2 + a3);

                    if (u == 7)
                        bp = __int_as_float(__builtin_amdgcn_ds_bpermute(
                                rowbase, __float_as_int(s)));
                }
            }

            // gold sidecar: transitions LEAVING t, next carried (chunks visited descending)
            {
                const int* tg = &TG[pb][r * CH];
                const int t4 = j * 4;
                const float* fbase = &FB[pb * FBW + r * ROWW];
                const int nlast = (j == 15) ? edgeRow[r] : tg[t4 + 4];
#pragma unroll
                for (int q = 0; q < 4; ++q) {
                    const int tc = tg[t4 + q];
                    const int tn = (q == 3) ? nlast : tg[t4 + q + 1];
                    gold += TlS[tn * K_TAGS + tc];
                    gold += fbase[(t4 + q) * 16 + tc];
                }
                if (j == 0) edgeRow[r] = tg[0];  // ends as tags[2048]
            }
        }
    }

    // ---- epilogue: reduce gold over the 16-lane row, dump half-state to workspace ----
    float gg = gold;
#pragma unroll
    for (int dd = 1; dd < 16; dd <<= 1) gg += __shfl_xor(gg, dd, 16);

    const int b = bbase + r;
    if (!half) {
        ws[WS_VF + b * 16 + j] = s;
        if (j == 0) {
            ((int*)ws)[WS_CF + b] = Cacc;
            // straddling transition tags[2047] -> tags[2048]
            const int tn = tags[(size_t)b * T_LEN + (T_LEN / 2)];
            ws[WS_GF + b] = gg + TlS[tn * K_TAGS + edgeRow[r]];
        }
    } else {
        ws[WS_VB + b * 16 + j] = s;
        if (j == 0) {
            ((int*)ws)[WS_CB + b] = Cacc;
            ws[WS_GB + b] = gg;
        }
    }
}

__global__ __launch_bounds__(64) void crf_combine(
        const float* __restrict__ ws, float* __restrict__ out) {
    const int b = blockIdx.x * 64 + threadIdx.x;
    const float* vf = ws + WS_VF + b * 16;
    const float* vb = ws + WS_VB + b * 16;
    float dot = 0.0f;
#pragma unroll
    for (int t = 0; t < 16; ++t) dot = fmaf(vf[t], vb[t], dot);
    const int cf = ((const int*)ws)[WS_CF + b];
    const int cb = ((const int*)ws)[WS_CB + b];
    const float g = ws[WS_GF + b] + ws[WS_GB + b];
    out[b] = LN2 * (log2f(dot) + (float)(cf + cb)) - g;
}

extern "C" void kernel_launch(void* const* d_in, const int* in_sizes, int n_in,
                              void* d_out, int out_size, void* d_ws, size_t ws_size,
                              hipStream_t stream) {
    const float* feats = (const float*)d_in[0];
    const int* tags = (const int*)d_in[1];
    const float* trans = (const float*)d_in[2];
    float* out = (float*)d_out;
    float* ws = (float*)d_ws;

    crf_half_kernel<<<dim3(512), dim3(64), 0, stream>>>(feats, tags, trans, ws);
    crf_combine<<<dim3(B_TOT / 64), dim3(64), 0, stream>>>(ws, out);
}

// Round 2
// 421.916 us; speedup vs baseline: 1.5078x; 1.1313x over previous
//
#include <hip/hip_runtime.h>
#include <math.h>

#define B_TOT 1024
#define T_LEN 4096
#define K_TAGS 16
#define START_TAG 14
#define STOP_TAG 15

#define LOG2E 1.4426950408889634f
#define LN2 0.6931471805599453f

#define CH 64                 // timesteps per staged chunk
#define NCH (T_LEN / CH)      // 64 chunks total
#define NCHH (NCH / 2)        // 32 chunks per half
#define ROWW 1032             // padded words per batch-row per buffer (64*16 + 8)
#define FBW (4 * ROWW)        // words per buffer (4 batch rows)

// workspace layout (float indices)
#define WS_VF 0               // [1024*16] forward half-vectors
#define WS_VB 16384           // [1024*16] backward half-vectors
#define WS_GF 32768           // [1024] gold partial, forward (+boundary)
#define WS_GB 33792           // [1024] gold partial, backward
#define WS_CF 34816           // [1024] int: forward log2 scale
#define WS_CB 35840           // [1024] int: backward log2 scale

typedef __attribute__((address_space(1))) const void GVoid;
typedef __attribute__((address_space(3))) void LVoid;

// Fused-DPP matvec step, forward:  s = (M s) * ef ; also produces next step's
// ef (efn = 2^(fn*log2e + nc)) off the serial chain. Hazard discipline: the
// first DPP reads %s two instructions after block entry; %s itself was written
// at the END of the previous block => >=2 wait-state slots guaranteed.
#define MATVEC_FWD(SV, EFV, EFNV, FNV, NEGCV, ET)                                     \
  do {                                                                                \
    float a0_, a1_, a2_, a3_, efa_, efn_;                                             \
    asm("v_mul_f32 %[a0], %[s], %[e0]\n\t"                                            \
        "v_fma_f32 %[efa], %[fn], %[l2e], %[nc]\n\t"                                  \
        "v_mul_f32_dpp %[a1], %[s], %[e1] row_ror:1 row_mask:0xf bank_mask:0xf\n\t"   \
        "v_mul_f32_dpp %[a2], %[s], %[e2] row_ror:2 row_mask:0xf bank_mask:0xf\n\t"   \
        "v_mul_f32_dpp %[a3], %[s], %[e3] row_ror:3 row_mask:0xf bank_mask:0xf\n\t"   \
        "v_fmac_f32_dpp %[a0], %[s], %[e4] row_ror:4 row_mask:0xf bank_mask:0xf\n\t"  \
        "v_fmac_f32_dpp %[a1], %[s], %[e5] row_ror:5 row_mask:0xf bank_mask:0xf\n\t"  \
        "v_fmac_f32_dpp %[a2], %[s], %[e6] row_ror:6 row_mask:0xf bank_mask:0xf\n\t"  \
        "v_fmac_f32_dpp %[a3], %[s], %[e7] row_ror:7 row_mask:0xf bank_mask:0xf\n\t"  \
        "v_fmac_f32_dpp %[a0], %[s], %[e8] row_ror:8 row_mask:0xf bank_mask:0xf\n\t"  \
        "v_fmac_f32_dpp %[a1], %[s], %[e9] row_ror:9 row_mask:0xf bank_mask:0xf\n\t"  \
        "v_fmac_f32_dpp %[a2], %[s], %[e10] row_ror:10 row_mask:0xf bank_mask:0xf\n\t"\
        "v_fmac_f32_dpp %[a3], %[s], %[e11] row_ror:11 row_mask:0xf bank_mask:0xf\n\t"\
        "v_fmac_f32_dpp %[a0], %[s], %[e12] row_ror:12 row_mask:0xf bank_mask:0xf\n\t"\
        "v_fmac_f32_dpp %[a1], %[s], %[e13] row_ror:13 row_mask:0xf bank_mask:0xf\n\t"\
        "v_fmac_f32_dpp %[a2], %[s], %[e14] row_ror:14 row_mask:0xf bank_mask:0xf\n\t"\
        "v_fmac_f32_dpp %[a3], %[s], %[e15] row_ror:15 row_mask:0xf bank_mask:0xf\n\t"\
        "v_exp_f32 %[efn], %[efa]\n\t"                                                \
        "v_add_f32 %[a0], %[a0], %[a1]\n\t"                                           \
        "v_add_f32 %[a2], %[a2], %[a3]\n\t"                                           \
        "v_add_f32 %[a0], %[a0], %[a2]\n\t"                                           \
        "v_mul_f32 %[s], %[a0], %[ef]"                                                \
        : [s] "+v"(SV), [a0] "=&v"(a0_), [a1] "=&v"(a1_), [a2] "=&v"(a2_),            \
          [a3] "=&v"(a3_), [efa] "=&v"(efa_), [efn] "=&v"(efn_)                       \
        : [ef] "v"(EFV), [fn] "v"(FNV), [l2e] "v"(LOG2E), [nc] "v"(NEGCV),            \
          [e0] "v"(ET[0]), [e1] "v"(ET[1]), [e2] "v"(ET[2]), [e3] "v"(ET[3]),         \
          [e4] "v"(ET[4]), [e5] "v"(ET[5]), [e6] "v"(ET[6]), [e7] "v"(ET[7]),         \
          [e8] "v"(ET[8]), [e9] "v"(ET[9]), [e10] "v"(ET[10]), [e11] "v"(ET[11]),     \
          [e12] "v"(ET[12]), [e13] "v"(ET[13]), [e14] "v"(ET[14]), [e15] "v"(ET[15]));\
    EFNV = efn_;                                                                      \
  } while (0)

// Backward (transposed) step:  s = M^T (s * ef).  us written at slot 0, first
// DPP reads it at slot 3 => 2 intervening instructions (hazard-safe).
#define MATVEC_BWD(SV, EFV, EFNV, FNV, NEGCV, ET)                                     \
  do {                                                                                \
    float a0_, a1_, a2_, a3_, efa_, efn_, us_;                                        \
    asm("v_mul_f32 %[us], %[s], %[ef]\n\t"                                            \
        "v_fma_f32 %[efa], %[fn], %[l2e], %[nc]\n\t"                                  \
        "v_mul_f32 %[a0], %[us], %[e0]\n\t"                                           \
        "v_mul_f32_dpp %[a1], %[us], %[e1] row_ror:1 row_mask:0xf bank_mask:0xf\n\t"  \
        "v_mul_f32_dpp %[a2], %[us], %[e2] row_ror:2 row_mask:0xf bank_mask:0xf\n\t"  \
        "v_mul_f32_dpp %[a3], %[us], %[e3] row_ror:3 row_mask:0xf bank_mask:0xf\n\t"  \
        "v_fmac_f32_dpp %[a0], %[us], %[e4] row_ror:4 row_mask:0xf bank_mask:0xf\n\t" \
        "v_fmac_f32_dpp %[a1], %[us], %[e5] row_ror:5 row_mask:0xf bank_mask:0xf\n\t" \
        "v_fmac_f32_dpp %[a2], %[us], %[e6] row_ror:6 row_mask:0xf bank_mask:0xf\n\t" \
        "v_fmac_f32_dpp %[a3], %[us], %[e7] row_ror:7 row_mask:0xf bank_mask:0xf\n\t" \
        "v_fmac_f32_dpp %[a0], %[us], %[e8] row_ror:8 row_mask:0xf bank_mask:0xf\n\t" \
        "v_fmac_f32_dpp %[a1], %[us], %[e9] row_ror:9 row_mask:0xf bank_mask:0xf\n\t" \
        "v_fmac_f32_dpp %[a2], %[us], %[e10] row_ror:10 row_mask:0xf bank_mask:0xf\n\t"\
        "v_fmac_f32_dpp %[a3], %[us], %[e11] row_ror:11 row_mask:0xf bank_mask:0xf\n\t"\
        "v_fmac_f32_dpp %[a0], %[us], %[e12] row_ror:12 row_mask:0xf bank_mask:0xf\n\t"\
        "v_fmac_f32_dpp %[a1], %[us], %[e13] row_ror:13 row_mask:0xf bank_mask:0xf\n\t"\
        "v_fmac_f32_dpp %[a2], %[us], %[e14] row_ror:14 row_mask:0xf bank_mask:0xf\n\t"\
        "v_fmac_f32_dpp %[a3], %[us], %[e15] row_ror:15 row_mask:0xf bank_mask:0xf\n\t"\
        "v_exp_f32 %[efn], %[efa]\n\t"                                                \
        "v_add_f32 %[a0], %[a0], %[a1]\n\t"                                           \
        "v_add_f32 %[a2], %[a2], %[a3]\n\t"                                           \
        "v_add_f32 %[s], %[a0], %[a2]"                                                \
        : [s] "+v"(SV), [us] "=&v"(us_), [a0] "=&v"(a0_), [a1] "=&v"(a1_),            \
          [a2] "=&v"(a2_), [a3] "=&v"(a3_), [efa] "=&v"(efa_), [efn] "=&v"(efn_)      \
        : [ef] "v"(EFV), [fn] "v"(FNV), [l2e] "v"(LOG2E), [nc] "v"(NEGCV),            \
          [e0] "v"(ET[0]), [e1] "v"(ET[1]), [e2] "v"(ET[2]), [e3] "v"(ET[3]),         \
          [e4] "v"(ET[4]), [e5] "v"(ET[5]), [e6] "v"(ET[6]), [e7] "v"(ET[7]),         \
          [e8] "v"(ET[8]), [e9] "v"(ET[9]), [e10] "v"(ET[10]), [e11] "v"(ET[11]),     \
          [e12] "v"(ET[12]), [e13] "v"(ET[13]), [e14] "v"(ET[14]), [e15] "v"(ET[15]));\
    EFNV = efn_;                                                                      \
  } while (0)

// Bidirectional bilinear split: result = log( r^T A2 A1 e_START ), r = exp(trans[STOP,:]).
// Blocks 0..255: forward half; 256..511: backward (transposed) half.
__global__ __launch_bounds__(64, 1) void crf_half_kernel(
        const float* __restrict__ feats,
        const int* __restrict__ tags,
        const float* __restrict__ trans,
        float* __restrict__ ws) {
    __shared__ float FBraw[128 + 2 * FBW + 160];  // +128 leading slack for backward ring underrun
    __shared__ int TG[2][4 * CH];                 // tag buffers
    __shared__ float TlS[K_TAGS * K_TAGS];        // raw transitions
    __shared__ int edgeRow[4];                    // gold chain carry

    float* const FB = FBraw + 128;

    const int lane = threadIdx.x;
    const int r = lane >> 4;
    const int j = lane & 15;
    const int half = blockIdx.x >> 8;             // 0 = forward, 1 = backward
    const int bbase = (blockIdx.x & 255) * 4;

    for (int i = lane; i < K_TAGS * K_TAGS; i += 64) TlS[i] = trans[i];
    if (lane < 4) edgeRow[lane] = half ? STOP_TAG : START_TAG;
    __syncthreads();

    // --- DPP direction probe: after row_ror:1, lane j holds value from lane (j+d)&15 ---
    const int pv = __builtin_amdgcn_mov_dpp(j, 0x121, 0xF, 0xF, false);
    const int d = (pv - j) & 15;  // 1 or 15

    // et[i] pairs with row_ror:i: rotated vector delivers x[(j + d*i)&15].
    float et[K_TAGS];
#pragma unroll
    for (int i = 0; i < K_TAGS; ++i) {
        const int src = (j + d * i) & 15;
        et[i] = exp2f(TlS[half ? (src * K_TAGS + j) : (j * K_TAGS + src)] * LOG2E);
    }

    const int rowbase = (lane & ~15) << 2;  // byte index of lane r*16 (bpermute)

    auto stage = [&](int c, int pb) {
        const int t0 = c * CH;
#pragma unroll
        for (int i = 0; i < 16; ++i) {
            const int row = i >> 2, seg = i & 3;
            const float* g = feats + ((size_t)(bbase + row) * T_LEN + t0) * K_TAGS
                             + seg * 256 + lane * 4;
            const float* l = &FB[pb * FBW + row * ROWW + seg * 256];
            __builtin_amdgcn_global_load_lds((GVoid*)g, (LVoid*)l, 16, 0, 0);
        }
#pragma unroll
        for (int row = 0; row < 4; ++row) {
            const int* g = tags + (size_t)(bbase + row) * T_LEN + t0 + lane;
            const int* l = &TG[pb][row * CH];
            __builtin_amdgcn_global_load_lds((GVoid*)g, (LVoid*)l, 4, 0, 0);
        }
    };

    float s = half ? exp2f(TlS[STOP_TAG * K_TAGS + j] * LOG2E)
                   : ((j == START_TAG) ? 1.0f : 0.0f);
    int Cacc = 0;        // accumulated log2 scale (exact int)
    float bp = 1.0f;     // row-reference (lane 0 of row), captured every 8th step
    float ef = 1.0f;     // current step's emission factor (pipelined one step ahead)
    float gold = 0.0f;

    if (!half) {
        // ===================== FORWARD HALF: chunks 0..31 =====================
        stage(0, 0);
        for (int c = 0; c < NCHH; ++c) {
            const int pb = c & 1;
            if (c + 1 < NCHH) {
                stage(c + 1, pb ^ 1);
                __builtin_amdgcn_s_waitcnt(0x4F74);  // vmcnt<=20
            } else {
                __builtin_amdgcn_s_waitcnt(0x0F70);  // vmcnt(0)
            }
            __builtin_amdgcn_sched_barrier(0);

            const float* fp = &FB[pb * FBW + r * ROWW + j];
            float fr[8];
#pragma unroll
            for (int u = 0; u < 8; ++u) fr[u] = fp[u * 16];
            ef = exp2f(fmaf(fr[0], LOG2E, -4.0f));  // prime this chunk's first ef

            for (int tb = 0; tb < CH; tb += 8) {
                const float* fq = fp + (tb + 8) * 16;  // refill base (overrun -> slack)
#pragma unroll
                for (int u = 0; u < 8; ++u) {
                    const float fn = fr[(u + 1) & 7];  // next step's feat (u==7 -> refilled fr[0])
                    fr[u] = fq[u * 16];

                    float negc;
                    if (u == 6) {
                        // prep u==7's rescale from bp captured 7 steps ago
                        const int kprev = (((__float_as_int(bp) >> 23) & 0xFF) - 127);
                        Cacc += 32 + kprev;
                        negc = -(4.0f + (float)kprev);
                    } else {
                        negc = -4.0f;
                    }

                    float efn;
                    MATVEC_FWD(s, ef, efn, fn, negc, et);
                    ef = efn;

                    if (u == 7)
                        bp = __int_as_float(__builtin_amdgcn_ds_bpermute(
                                rowbase, __float_as_int(s)));
                }
            }

            // gold sidecar: transitions ENTERING t; lane j owns [4j, 4j+4)
            {
                const int* tg = &TG[pb][r * CH];
                const int t4 = j * 4;
                const int pidx = (j == 0) ? 0 : (t4 - 1);
                const int pval = tg[pidx];
                int prev = (j == 0) ? edgeRow[r] : pval;
                const float* fbase = &FB[pb * FBW + r * ROWW];
#pragma unroll
                for (int q = 0; q < 4; ++q) {
                    const int tc = tg[t4 + q];
                    gold += TlS[tc * K_TAGS + prev];
                    gold += fbase[(t4 + q) * 16 + tc];
                    prev = tc;
                }
                if (j == 15) edgeRow[r] = prev;  // ends as tags[2047]
            }
        }
    } else {
        // ===================== BACKWARD HALF: chunks 63..32 =====================
        stage(NCH - 1, 0);
        for (int ii = 0; ii < NCHH; ++ii) {
            const int pb = ii & 1;
            if (ii + 1 < NCHH) {
                stage(NCH - 2 - ii, pb ^ 1);
                __builtin_amdgcn_s_waitcnt(0x4F74);  // vmcnt<=20
            } else {
                __builtin_amdgcn_s_waitcnt(0x0F70);  // vmcnt(0)
            }
            __builtin_amdgcn_sched_barrier(0);

            const float* fp = &FB[pb * FBW + r * ROWW + j];
            float fr[8];
#pragma unroll
            for (int u = 0; u < 8; ++u) fr[u] = fp[(CH - 1 - u) * 16];
            ef = exp2f(fmaf(fr[0], LOG2E, -4.0f));  // prime

            for (int tb = 0; tb < CH; tb += 8) {
                const float* fq = fp + (CH - 9 - tb) * 16;  // fr[u] <- t_loc 55-tb-u (underrun -> slack)
#pragma unroll
                for (int u = 0; u < 8; ++u) {
                    const float fn = fr[(u + 1) & 7];
                    fr[u] = fq[-(u * 16)];

                    float negc;
                    if (u == 6) {
                        const int kprev = (((__float_as_int(bp) >> 23) & 0xFF) - 127);
                        Cacc += 32 + kprev;
                        negc = -(4.0f + (float)kprev);
                    } else {
                        negc = -4.0f;
                    }

                    float efn;
                    MATVEC_BWD(s, ef, efn, fn, negc, et);
                    ef = efn;

                    if (u == 7)
                        bp = __int_as_float(__builtin_amdgcn_ds_bpermute(
                                rowbase, __float_as_int(s)));
                }
            }

            // gold sidecar: transitions LEAVING t, next carried (chunks descending)
            {
                const int* tg = &TG[pb][r * CH];
                const int t4 = j * 4;
                const float* fbase = &FB[pb * FBW + r * ROWW];
                const int nlast = (j == 15) ? edgeRow[r] : tg[t4 + 4];
#pragma unroll
                for (int q = 0; q < 4; ++q) {
                    const int tc = tg[t4 + q];
                    const int tn = (q == 3) ? nlast : tg[t4 + q + 1];
                    gold += TlS[tn * K_TAGS + tc];
                    gold += fbase[(t4 + q) * 16 + tc];
                }
                if (j == 0) edgeRow[r] = tg[0];  // ends as tags[2048]
            }
        }
    }

    // ---- epilogue: reduce gold over the 16-lane row, dump half-state to workspace ----
    float gg = gold;
#pragma unroll
    for (int dd = 1; dd < 16; dd <<= 1) gg += __shfl_xor(gg, dd, 16);

    const int b = bbase + r;
    if (!half) {
        ws[WS_VF + b * 16 + j] = s;
        if (j == 0) {
            ((int*)ws)[WS_CF + b] = Cacc;
            const int tn = tags[(size_t)b * T_LEN + (T_LEN / 2)];
            ws[WS_GF + b] = gg + TlS[tn * K_TAGS + edgeRow[r]];
        }
    } else {
        ws[WS_VB + b * 16 + j] = s;
        if (j == 0) {
            ((int*)ws)[WS_CB + b] = Cacc;
            ws[WS_GB + b] = gg;
        }
    }
}

__global__ __launch_bounds__(64) void crf_combine(
        const float* __restrict__ ws, float* __restrict__ out) {
    const int b = blockIdx.x * 64 + threadIdx.x;
    const float* vf = ws + WS_VF + b * 16;
    const float* vb = ws + WS_VB + b * 16;
    float dot = 0.0f;
#pragma unroll
    for (int t = 0; t < 16; ++t) dot = fmaf(vf[t], vb[t], dot);
    const int cf = ((const int*)ws)[WS_CF + b];
    const int cb = ((const int*)ws)[WS_CB + b];
    const float g = ws[WS_GF + b] + ws[WS_GB + b];
    out[b] = LN2 * (log2f(dot) + (float)(cf + cb)) - g;
}

extern "C" void kernel_launch(void* const* d_in, const int* in_sizes, int n_in,
                              void* d_out, int out_size, void* d_ws, size_t ws_size,
                              hipStream_t stream) {
    const float* feats = (const float*)d_in[0];
    const int* tags = (const int*)d_in[1];
    const float* trans = (const float*)d_in[2];
    float* out = (float*)d_out;
    float* ws = (float*)d_ws;

    crf_half_kernel<<<dim3(512), dim3(64), 0, stream>>>(feats, tags, trans, ws);
    crf_combine<<<dim3(B_TOT / 64), dim3(64), 0, stream>>>(ws, out);
}